// Round 2
// baseline (331.663 us; speedup 1.0000x reference)
//
#include <hip/hip_runtime.h>
#include <hip/hip_bf16.h>

typedef short short8 __attribute__((ext_vector_type(8)));
typedef float f32x4 __attribute__((ext_vector_type(4)));

#define MFMA(a, b, c) __builtin_amdgcn_mfma_f32_16x16x32_bf16((a), (b), (c), 0, 0, 0)

#define NB 2
#define NS 1024
#define NHID 768
#define NHEAD 12
#define NDH 64

__device__ __forceinline__ short f2bf(float x) {
    __hip_bfloat16 h = __float2bfloat16(x);
    return *reinterpret_cast<short*>(&h);
}

__device__ __forceinline__ short8 ld8f32_bf(const float* __restrict__ p) {
    const f32x4* q = reinterpret_cast<const f32x4*>(p);
    f32x4 a = q[0], b = q[1];
    short8 r;
    r[0] = f2bf(a[0]); r[1] = f2bf(a[1]); r[2] = f2bf(a[2]); r[3] = f2bf(a[3]);
    r[4] = f2bf(b[0]); r[5] = f2bf(b[1]); r[6] = f2bf(b[2]); r[7] = f2bf(b[3]);
    return r;
}

typedef const __attribute__((address_space(1))) void gas_t;
typedef __attribute__((address_space(3))) void las_t;
__device__ __forceinline__ void gld_lds16(const float* g, float* l) {
    __builtin_amdgcn_global_load_lds((gas_t*)g, (las_t*)l, 16, 0, 0);
}

// ---------------------------------------------------------------------------
// Kernel 1: QKV projection (unchanged from R0). Q,K row-major bf16; V stored
// transposed per head VT[b][h][d][s].
// ---------------------------------------------------------------------------
__global__ __launch_bounds__(256, 2) void qkv_proj(
    const float* __restrict__ hidden,
    const float* __restrict__ Wq, const float* __restrict__ bq,
    const float* __restrict__ Wk, const float* __restrict__ bk,
    const float* __restrict__ Wv, const float* __restrict__ bv,
    short* __restrict__ Qo, short* __restrict__ Ko, short* __restrict__ VTo)
{
    const int lane = threadIdx.x & 63;
    const int wave = threadIdx.x >> 6;
    const int lg = lane >> 4, lr = lane & 15;

    const int m0 = blockIdx.x * 64 + wave * 16;
    const int n0 = blockIdx.y * 64;
    const int proj = n0 / NHID;
    const int ncol0 = n0 % NHID;
    const float* W = proj == 0 ? Wq : (proj == 1 ? Wk : Wv);
    const float* bias = proj == 0 ? bq : (proj == 1 ? bk : bv);

    f32x4 acc[4];
    #pragma unroll
    for (int s = 0; s < 4; ++s) acc[s] = (f32x4){0.f, 0.f, 0.f, 0.f};

    const float* arow = hidden + (size_t)(m0 + lr) * NHID;
    for (int k0 = 0; k0 < NHID; k0 += 32) {
        short8 afrag = ld8f32_bf(arow + k0 + lg * 8);
        #pragma unroll
        for (int s = 0; s < 4; ++s) {
            const float* bp = W + (size_t)(ncol0 + s * 16 + lr) * NHID + k0 + lg * 8;
            short8 bfrag = ld8f32_bf(bp);
            acc[s] = MFMA(afrag, bfrag, acc[s]);
        }
    }

    #pragma unroll
    for (int s = 0; s < 4; ++s) {
        const int ncol = ncol0 + s * 16 + lr;
        const float badd = bias[ncol];
        #pragma unroll
        for (int r = 0; r < 4; ++r) {
            const int m = m0 + lg * 4 + r;
            const short v16 = f2bf(acc[s][r] + badd);
            if (proj == 0) {
                Qo[(size_t)m * NHID + ncol] = v16;
            } else if (proj == 1) {
                Ko[(size_t)m * NHID + ncol] = v16;
            } else {
                const int b = m >> 10, ss = m & 1023;
                const int h = ncol >> 6, dd = ncol & 63;
                VTo[(((size_t)(b * NHEAD + h) * NDH + dd) << 10) + ss] = v16;
            }
        }
    }
}

// ---------------------------------------------------------------------------
// Kernel 2: bias GEMM — biasO[b][n][i][j] = q[b,n,i,:]·bbox[i,j,b,:]
// One wg per (b,i); 4 waves split j into quarters. bbox streamed via
// global_load_lds (16B) into wave-private double-buffered LDS tiles with
// 16B-granular XOR swizzle (k ^= j&7) pre-applied on the GLOBAL source so
// the linear DMA dest + swizzled ds_read pair is conflict-reduced.
// Counted vmcnt: t=0 -> 8, 1..6 -> 16 (8 stores(t-1) + 8 DMA(t+1) younger
// than DMA(t)), t=7 -> 8. No barriers (wave-private buffers).
// ---------------------------------------------------------------------------
__global__ __launch_bounds__(256, 2) void bias_gemm(
    const short* __restrict__ Q,      // (2,1024,768) bf16
    const float* __restrict__ bbox,   // (1024,1024,2,64) f32
    float* __restrict__ biasO)        // (2,12,1024,1024) f32
{
    const int lane = threadIdx.x & 63;
    const int wave = threadIdx.x >> 6;
    const int lg = lane >> 4, lr = lane & 15;
    const int bi = blockIdx.x;              // b*1024 + i
    const int b = bi >> 10, i = bi & 1023;
    const int jq = wave * 256;

    __shared__ float lds[4][2][32 * 64];    // per-wave dbuf: 32 j-rows x 64 d

    // A-frag: m = head (lane lr; rows 12..15 garbage, dropped), k = d.
    // lr*64+kk*32+lg*8 can overread row end by <1024 shorts -> lands in K
    // region of ws (benign).
    short8 qa[2];
    #pragma unroll
    for (int kk = 0; kk < 2; ++kk)
        qa[kk] = *reinterpret_cast<const short8*>(
            Q + (size_t)bi * NHID + lr * 64 + kk * 32 + lg * 8);

    const int jrow = lane >> 4;             // reused: c>>4 with c = w*64+lane
    const int q16 = lane & 15;

    auto stage = [&](int t, int buf) {
        const int j0 = jq + t * 32;
        float* dst = &lds[wave][buf][0];
        #pragma unroll
        for (int w = 0; w < 8; ++w) {
            const int jr = w * 4 + jrow;            // 0..31
            const int kg = q16 ^ (jr & 7);          // source pre-swizzle
            const float* src = bbox + ((size_t)(i * NS + j0 + jr) * NB + b) * NDH + kg * 4;
            gld_lds16(src, dst + w * 256);          // HW adds lane*16B
        }
    };

    auto compute = [&](int t, int buf) {
        const float* tile = &lds[wave][buf][0];
        const int x = lr & 7;
        #pragma unroll
        for (int s = 0; s < 2; ++s) {
            const int jl = s * 16 + lr;
            f32x4 c = (f32x4){0.f, 0.f, 0.f, 0.f};
            #pragma unroll
            for (int kk = 0; kk < 2; ++kk) {
                const int m = kk * 4 + lg;
                f32x4 ca = *reinterpret_cast<const f32x4*>(tile + jl * 64 + ((2 * m) ^ x) * 4);
                f32x4 cb = *reinterpret_cast<const f32x4*>(tile + jl * 64 + ((2 * m + 1) ^ x) * 4);
                short8 bf;
                bf[0] = f2bf(ca[0]); bf[1] = f2bf(ca[1]); bf[2] = f2bf(ca[2]); bf[3] = f2bf(ca[3]);
                bf[4] = f2bf(cb[0]); bf[5] = f2bf(cb[1]); bf[6] = f2bf(cb[2]); bf[7] = f2bf(cb[3]);
                c = MFMA(qa[kk], bf, c);
            }
            if (lg < 3) {                            // heads n = lg*4+r < 12
                #pragma unroll
                for (int r = 0; r < 4; ++r) {
                    const int n = lg * 4 + r;
                    biasO[((size_t)(b * NHEAD + n) * NS + i) * NS + jq + t * 32 + s * 16 + lr] = c[r];
                }
            }
        }
    };

    stage(0, 0);
    #pragma unroll
    for (int t = 0; t < 8; ++t) {
        const int buf = t & 1;
        // prior tile's ds_reads drained before overwriting that buffer next
        asm volatile("s_waitcnt lgkmcnt(0)" ::: "memory");
        if (t < 7) stage(t + 1, buf ^ 1);
        if (t == 0)          asm volatile("s_waitcnt vmcnt(8)"  ::: "memory");
        else if (t < 7)      asm volatile("s_waitcnt vmcnt(16)" ::: "memory");
        else                 asm volatile("s_waitcnt vmcnt(8)"  ::: "memory");
        compute(t, buf);
    }
}

// ---------------------------------------------------------------------------
// Kernel 3: attention given precomputed bias. wg = (i-tile 16, b*12+h);
// 4 waves split j into quarters of 256; partial num/den combined in LDS;
// writes out directly (no global partials, no combine kernel).
// ---------------------------------------------------------------------------
__global__ __launch_bounds__(256, 4) void attn2(
    const short* __restrict__ Q,
    const short* __restrict__ K,
    const short* __restrict__ VT,
    const float* __restrict__ biasO,
    const float* __restrict__ mask,
    float* __restrict__ out)
{
    const int lane = threadIdx.x & 63;
    const int wave = threadIdx.x >> 6;
    const int lg = lane >> 4, lr = lane & 15;
    const int i0 = blockIdx.x * 16;
    const int bh = blockIdx.y;
    const int b = bh / NHEAD, h = bh % NHEAD;
    const int jq = wave * 256;

    __shared__ short plds[4][16][40];
    __shared__ float numlds[4][16][68];
    __shared__ float denlds[4][16];

    short8 qa[2];
    #pragma unroll
    for (int kk = 0; kk < 2; ++kk)
        qa[kk] = *reinterpret_cast<const short8*>(
            Q + ((size_t)(b * NS) + i0 + lr) * NHID + h * 64 + kk * 32 + lg * 8);

    f32x4 ctx[4];
    #pragma unroll
    for (int dt = 0; dt < 4; ++dt) ctx[dt] = (f32x4){0.f, 0.f, 0.f, 0.f};
    f32x4 den = (f32x4){0.f, 0.f, 0.f, 0.f};

    #pragma unroll 2
    for (int t = 0; t < 8; ++t) {
        const int j0 = jq + t * 32;
        f32x4 sc[2];
        #pragma unroll
        for (int s = 0; s < 2; ++s) {
            f32x4 c = (f32x4){0.f, 0.f, 0.f, 0.f};
            #pragma unroll
            for (int kk = 0; kk < 2; ++kk) {
                short8 kf = *reinterpret_cast<const short8*>(
                    K + ((size_t)(b * NS) + j0 + s * 16 + lr) * NHID + h * 64 + kk * 32 + lg * 8);
                c = MFMA(qa[kk], kf, c);
            }
            sc[s] = c;
        }
        const float mk0 = mask[b * NS + j0 + lr];
        const float mk1 = mask[b * NS + j0 + 16 + lr];
        #pragma unroll
        for (int s = 0; s < 2; ++s) {
            const float mk = s == 0 ? mk0 : mk1;
            #pragma unroll
            for (int r = 0; r < 4; ++r) {
                const int i = i0 + lg * 4 + r;
                const float bb = biasO[((size_t)(b * NHEAD + h) * NS + i) * NS + j0 + s * 16 + lr];
                sc[s][r] = __expf((sc[s][r] + bb) * 0.125f + mk);
            }
        }
        den += sc[0] + sc[1];

        #pragma unroll
        for (int s = 0; s < 2; ++s)
            #pragma unroll
            for (int r = 0; r < 4; ++r)
                plds[wave][lg * 4 + r][s * 16 + lr] = f2bf(sc[s][r]);
        asm volatile("" ::: "memory");
        short8 pa = *reinterpret_cast<const short8*>(&plds[wave][lr][lg * 8]);
        asm volatile("" ::: "memory");

        #pragma unroll
        for (int dt = 0; dt < 4; ++dt) {
            short8 vf = *reinterpret_cast<const short8*>(
                VT + ((size_t)(b * NHEAD + h) * NDH + dt * 16 + lr) * NS + j0 + lg * 8);
            ctx[dt] = MFMA(pa, vf, ctx[dt]);
        }
    }

    // reduce den over the 16 j-lanes (lr)
    #pragma unroll
    for (int w = 1; w < 16; w <<= 1) {
        f32x4 o;
        #pragma unroll
        for (int r = 0; r < 4; ++r) o[r] = __shfl_xor(den[r], w, 64);
        den += o;
    }

    // per-wave partials -> LDS
    #pragma unroll
    for (int dt = 0; dt < 4; ++dt)
        #pragma unroll
        for (int r = 0; r < 4; ++r)
            numlds[wave][lg * 4 + r][dt * 16 + lr] = ctx[dt][r];
    if (lr == 0) {
        #pragma unroll
        for (int r = 0; r < 4; ++r) denlds[wave][lg * 4 + r] = den[r];
    }
    __syncthreads();

    // combine 4 waves, divide, store
    const int ti = threadIdx.x >> 4;
    const int tc = (threadIdx.x & 15) * 4;
    f32x4 n = *reinterpret_cast<const f32x4*>(&numlds[0][ti][tc]);
    n += *reinterpret_cast<const f32x4*>(&numlds[1][ti][tc]);
    n += *reinterpret_cast<const f32x4*>(&numlds[2][ti][tc]);
    n += *reinterpret_cast<const f32x4*>(&numlds[3][ti][tc]);
    const float dd = denlds[0][ti] + denlds[1][ti] + denlds[2][ti] + denlds[3][ti];
    const float inv = 1.0f / dd;
    f32x4 o = n * inv;
    *reinterpret_cast<f32x4*>(out + ((size_t)(b * NS) + i0 + ti) * NHID + h * 64 + tc) = o;
}

extern "C" void kernel_launch(void* const* d_in, const int* in_sizes, int n_in,
                              void* d_out, int out_size, void* d_ws, size_t ws_size,
                              hipStream_t stream) {
    (void)in_sizes; (void)n_in; (void)out_size; (void)ws_size;
    const float* hidden = (const float*)d_in[0];
    const float* bbox   = (const float*)d_in[1];
    const float* mask   = (const float*)d_in[2];
    const float* Wq = (const float*)d_in[3]; const float* bq = (const float*)d_in[4];
    const float* Wk = (const float*)d_in[5]; const float* bk = (const float*)d_in[6];
    const float* Wv = (const float*)d_in[7]; const float* bv = (const float*)d_in[8];
    float* out = (float*)d_out;

    char* ws = (char*)d_ws;
    const size_t qkv_bytes = (size_t)NB * NS * NHID * sizeof(short); // 3,145,728
    short* Qw  = (short*)ws;
    short* Kw  = (short*)(ws + qkv_bytes);
    short* VTw = (short*)(ws + 2 * qkv_bytes);
    float* biasW = (float*)(ws + 3 * qkv_bytes);  // (2,12,1024,1024) f32 = 100.7 MB

    dim3 gp(32, 36);
    qkv_proj<<<gp, 256, 0, stream>>>(hidden, Wq, bq, Wk, bk, Wv, bv, Qw, Kw, VTw);

    bias_gemm<<<NB * NS, 256, 0, stream>>>(Qw, bbox, biasW);

    dim3 ga(NS / 16, NB * NHEAD);
    attn2<<<ga, 256, 0, stream>>>(Qw, Kw, VTw, biasW, mask, out);
}